// Round 5
// baseline (327.517 us; speedup 1.0000x reference)
//
#include <hip/hip_runtime.h>
#include <math.h>
#include <stdint.h>

#define NTOT   8192
#define HALF_N 4096
#define DIM    512
#define INV_T  14.2857142857142857f   // 1/0.07
#define NTILE  64                     // 8192 / 128
#define NBLK   2080                   // 64*65/2 triangular; 2080 % 8 == 0

using s16x8 = __attribute__((ext_vector_type(8))) short;
using f32x4 = __attribute__((ext_vector_type(4))) float;

// Scratch in static device globals (fully rewritten every call; no d_ws use).
__device__ unsigned short g_fnb[NTOT * DIM];   // normalized bf16 matrix, 8 MB
__device__ float g_pos[NTOT];
__device__ float g_ps[(size_t)NTILE * NTOT];   // per-slot sumexp partials, 2 MB
__device__ int   g_pc[(size_t)NTILE * NTOT];   // per-slot count partials, 2 MB
__device__ float g_part4[32 * 4];              // per-block scalar partials (kredfin)
__device__ int   g_tick2;                      // kredfin last-block ticket

// super-tile decode tables: 4x4 upper-triangle of 16x16 slab groups.
// sizes: diag super = 136 (16*17/2), full super = 256. (R4-verified decode.)
__constant__ int c_pre[11] = {0,136,392,648,904,1040,1296,1552,1688,1944,2080};
__constant__ int c_gi[10]  = {0,0,0,0,1,1,1,2,2,3};
__constant__ int c_gj[10]  = {0,1,2,3,1,2,3,2,3,3};

__device__ __forceinline__ float bf2f(unsigned short u) {
  union { unsigned int i; float f; } v; v.i = ((unsigned int)u) << 16; return v.f;
}
__device__ __forceinline__ unsigned short f2bf(float x) {
  union { float f; unsigned int i; } v; v.f = x;
  unsigned int u = v.i;
  return (unsigned short)((u + 0x7FFFu + ((u >> 16) & 1u)) >> 16);
}

// async global->LDS, 16 B per lane. LDS dest is wave-uniform base + lane*16.
__device__ __forceinline__ void gload16(const unsigned short* g, unsigned short* l) {
  __builtin_amdgcn_global_load_lds(
      (const __attribute__((address_space(1))) unsigned int*)g,
      (__attribute__((address_space(3))) unsigned int*)l, 16, 0, 0);
}

// ---------------- kernel 1: normalize pairs -> bf16, pos, reset ticket ----------------
__global__ __launch_bounds__(256) void knorm(const float* __restrict__ f1,
                                             const float* __restrict__ f2) {
  const int tid  = threadIdx.x;
  const int wv   = tid >> 6;
  const int pi   = wv >> 1;            // pair within block
  const int half = wv & 1;             // 0: f1 row, 1: f2 row
  const int lane = tid & 63;
  const int b    = blockIdx.x * 2 + pi;
  const int row  = b + half * HALF_N;

  if (blockIdx.x == 0 && tid == 0)
    __hip_atomic_store(&g_tick2, 0, __ATOMIC_RELAXED, __HIP_MEMORY_SCOPE_AGENT);

  const float* src = (half == 0) ? (f1 + (size_t)b * DIM) : (f2 + (size_t)b * DIM);
  float4 v0 = ((const float4*)src)[lane];
  float4 v1 = ((const float4*)src)[lane + 64];
  float ss = v0.x*v0.x + v0.y*v0.y + v0.z*v0.z + v0.w*v0.w
           + v1.x*v1.x + v1.y*v1.y + v1.z*v1.z + v1.w*v1.w;
  #pragma unroll
  for (int o = 32; o >= 1; o >>= 1) ss += __shfl_xor(ss, o, 64);
  const float sc = 1.0f / fmaxf(sqrtf(ss), 1e-8f);
  ushort4 h0, h1;
  h0.x = f2bf(v0.x * sc); h0.y = f2bf(v0.y * sc);
  h0.z = f2bf(v0.z * sc); h0.w = f2bf(v0.w * sc);
  h1.x = f2bf(v1.x * sc); h1.y = f2bf(v1.y * sc);
  h1.z = f2bf(v1.z * sc); h1.w = f2bf(v1.w * sc);
  ushort4* dst = (ushort4*)(g_fnb + (size_t)row * DIM);
  dst[lane]      = h0;
  dst[lane + 64] = h1;

  // pos[b] = <fn_b, fn_{b+4096}> on the same bf16 values the GEMM uses
  __shared__ ushort4 sh[2][64][2];
  if (half == 1) { sh[pi][lane][0] = h0; sh[pi][lane][1] = h1; }
  __syncthreads();
  if (half == 0) {
    const ushort4 p0 = sh[pi][lane][0], p1 = sh[pi][lane][1];
    float s = bf2f(h0.x)*bf2f(p0.x) + bf2f(h0.y)*bf2f(p0.y)
            + bf2f(h0.z)*bf2f(p0.z) + bf2f(h0.w)*bf2f(p0.w)
            + bf2f(h1.x)*bf2f(p1.x) + bf2f(h1.y)*bf2f(p1.y)
            + bf2f(h1.z)*bf2f(p1.z) + bf2f(h1.w)*bf2f(p1.w);
    #pragma unroll
    for (int o = 32; o >= 1; o >>= 1) s += __shfl_xor(s, o, 64);
    if (lane == 0) { g_pos[b] = s; g_pos[b + HALF_N] = s; }
  }
}

// ---------------- kernel 2: symmetric fused GEMM, atomic-free epilogue ----------------
// R5: R3's proven structure (plain slot stores, NO fences/tickets in the hot
// kernel -- R4 showed agent-scope acq_rel RMWs force per-XCD L2 writebacks,
// ~4000 of them serialized the memory pipe) + R4's proven super-tile schedule
// (16x16-slab supers keep each XCD's working set ~4 MB = one L2; FETCH
// 112->48 MB) + epilogue LDS aliased onto As (dead after K-loop) so
// LDS = exactly 32 KB -> 5 blocks/CU (was 4) for latency hiding.
__global__ __launch_bounds__(256, 5) void kmain() {
  __shared__ __align__(16) unsigned short As[128 * 64];   // 16 KB
  __shared__ __align__(16) unsigned short Bs[128 * 64];   // 16 KB
  // epilogue scratch aliased onto As (guarded by a barrier after the K-loop)
  float* sRowS = reinterpret_cast<float*>(As);            // 128 f
  int*   sRowC = reinterpret_cast<int*>(sRowS + 128);     // 128 i
  float* sColS = reinterpret_cast<float*>(sRowC + 128);   // 128 f
  int*   sColC = reinterpret_cast<int*>(sColS + 128);     // 128 i

  // XCD swizzle: contiguous t-range of 260 per XCD, then super-tile decode
  const int t_sw = (blockIdx.x & 7) * (NBLK / 8) + (blockIdx.x >> 3);
  int sp = 0;
  while (t_sw >= c_pre[sp + 1]) ++sp;
  int l = t_sw - c_pre[sp];
  int lbi, lbj;
  if (c_gi[sp] == c_gj[sp]) {          // diagonal super: triangular 16
    int r16 = 16; lbi = 0;
    while (l >= r16) { l -= r16; --r16; ++lbi; }
    lbj = lbi + l;
  } else {                             // full super: row-major (A-slab runs)
    lbi = l >> 4; lbj = l & 15;
  }
  const int bi = c_gi[sp] * 16 + lbi;
  const int bj = c_gj[sp] * 16 + lbj;
  const bool offdiag = (bi != bj);
  const int i0 = bi * 128, j0 = bj * 128;

  const int tid  = threadIdx.x;
  const int lane = tid & 63;
  const int w    = tid >> 6;
  const int wr   = (w >> 1) * 64;   // wave row base
  const int wc   = (w & 1) * 64;    // wave col base
  const int lrow = lane & 15;
  const int lq   = lane >> 4;

  // staging: wave w covers tile rows [w*32, w*32+32) in 4 chunks of 8 rows.
  // Linear LDS dest; inverse-XOR-swizzled global source (rule #21).
  const int rsub = lane >> 3;
  const int lcb  = (lane & 7) ^ rsub;
  const unsigned short* Ag = g_fnb + (size_t)(i0 + w * 32 + rsub) * DIM + lcb * 8;
  const unsigned short* Bg = g_fnb + (size_t)(j0 + w * 32 + rsub) * DIM + lcb * 8;
  unsigned short* Al = &As[w * 32 * 64];
  unsigned short* Bl = &Bs[w * 32 * 64];

  f32x4 acc[4][4];
  #pragma unroll
  for (int a = 0; a < 4; ++a)
    #pragma unroll
    for (int bb = 0; bb < 4; ++bb) { acc[a][bb][0]=0.f; acc[a][bb][1]=0.f; acc[a][bb][2]=0.f; acc[a][bb][3]=0.f; }

  const unsigned short* Bls = offdiag ? (const unsigned short*)Bs
                                      : (const unsigned short*)As;

  for (int kt = 0; kt < 8; ++kt) {
    __syncthreads();                       // prev compute done, LDS reusable
    const int kb = kt * 64;
    #pragma unroll
    for (int q = 0; q < 4; ++q) {
      gload16(Ag + (size_t)(q * 8) * DIM + kb, Al + q * 512);
      if (offdiag) gload16(Bg + (size_t)(q * 8) * DIM + kb, Bl + q * 512);
    }
    __syncthreads();                       // vmcnt(0) drains here -> tile kt visible

    #pragma unroll
    for (int kk = 0; kk < 2; ++kk) {
      s16x8 af[4], bf[4];
      #pragma unroll
      for (int mi = 0; mi < 4; ++mi) {
        const int r = wr + mi * 16 + lrow;
        af[mi] = *(const s16x8*)(&As[r * 64 + (((kk * 4 + lq) ^ (lrow & 7)) * 8)]);
      }
      #pragma unroll
      for (int ni = 0; ni < 4; ++ni) {
        const int r = wc + ni * 16 + lrow;
        bf[ni] = *(const s16x8*)(&Bls[r * 64 + (((kk * 4 + lq) ^ (lrow & 7)) * 8)]);
      }
      #pragma unroll
      for (int mi = 0; mi < 4; ++mi)
        #pragma unroll
        for (int ni = 0; ni < 4; ++ni)
          acc[mi][ni] = __builtin_amdgcn_mfma_f32_16x16x32_bf16(af[mi], bf[ni], acc[mi][ni], 0, 0, 0);
    }
  }

  // ---- epilogue: LDS-combine partials, plain slot stores (no global atomics) ----
  __syncthreads();   // all waves' LDS reads done -> safe to reuse As as scratch
  if (tid < 128) { sRowS[tid] = 0.f; sRowC[tid] = 0; sColS[tid] = 0.f; sColC[tid] = 0; }
  __syncthreads();

  // row side (always): 2 waves contribute per row (wc=0 / wc=64)
  #pragma unroll
  for (int mi = 0; mi < 4; ++mi) {
    #pragma unroll
    for (int r = 0; r < 4; ++r) {
      const int ridx = wr + mi * 16 + lq * 4 + r;     // 0..127
      const int i  = i0 + ridx;
      const float pv = g_pos[i];
      float s = 0.f; int c = 0;
      #pragma unroll
      for (int ni = 0; ni < 4; ++ni) {
        const int j = j0 + wc + ni * 16 + lrow;
        const float v = acc[mi][ni][r];
        const float e = __expf(v * INV_T);
        const bool diag = (j == i);
        s += diag ? 0.f : e;
        c += (!diag && (j != (i ^ HALF_N)) && (v > pv)) ? 1 : 0;
      }
      #pragma unroll
      for (int o = 1; o < 16; o <<= 1) {
        s += __shfl_xor(s, o, 64);
        c += __shfl_xor(c, o, 64);
      }
      if (lrow == 0) {
        atomicAdd(&sRowS[ridx], s);
        atomicAdd(&sRowC[ridx], c);
      }
    }
  }

  // col side (off-diagonal only): 2 waves contribute per col (wr=0 / wr=64)
  if (offdiag) {
    #pragma unroll
    for (int ni = 0; ni < 4; ++ni) {
      const int cidx = wc + ni * 16 + lrow;           // 0..127
      const int j  = j0 + cidx;
      const float pj = g_pos[j];
      float s = 0.f; int c = 0;
      #pragma unroll
      for (int mi = 0; mi < 4; ++mi) {
        #pragma unroll
        for (int r = 0; r < 4; ++r) {
          const int i = i0 + wr + mi * 16 + lq * 4 + r;
          const float v = acc[mi][ni][r];
          s += __expf(v * INV_T);
          c += ((i != (j ^ HALF_N)) && (v > pj)) ? 1 : 0;
        }
      }
      s += __shfl_xor(s, 16, 64); s += __shfl_xor(s, 32, 64);
      c += __shfl_xor(c, 16, 64); c += __shfl_xor(c, 32, 64);
      if (lq == 0) {
        atomicAdd(&sColS[cidx], s);
        atomicAdd(&sColC[cidx], c);
      }
    }
  }
  __syncthreads();

  // slot stores: row side -> slab bi slot bj; col side -> slab bj slot bi
  if (tid < 128) {
    g_ps[(size_t)bj * NTOT + i0 + tid] = sRowS[tid];
    g_pc[(size_t)bj * NTOT + i0 + tid] = sRowC[tid];
  } else if (offdiag && tid < 256) {
    const int r2 = tid - 128;
    g_ps[(size_t)bi * NTOT + j0 + r2] = sColS[r2];
    g_pc[(size_t)bi * NTOT + j0 + r2] = sColC[r2];
  }
}

// ---------------- kernel 3: fold slots + finalize (last-block ticket) ----------------
__global__ __launch_bounds__(256) void kredfin(float* __restrict__ out) {
  const int tid = threadIdx.x;
  const int i = blockIdx.x * 256 + tid;            // 32 blocks x 256 = 8192 rows
  float s = 0.f; int c = 0;
  #pragma unroll 8
  for (int sl = 0; sl < NTILE; ++sl) {
    s += g_ps[(size_t)sl * NTOT + i];
    c += g_pc[(size_t)sl * NTOT + i];
  }
  float nll = -g_pos[i] * INV_T + logf(s);
  float t1 = (c == 0) ? 1.f : 0.f;
  float t5 = (c < 5) ? 1.f : 0.f;
  float mr = (float)c;
  #pragma unroll
  for (int o = 32; o >= 1; o >>= 1) {
    nll += __shfl_xor(nll, o, 64);
    t1  += __shfl_xor(t1, o, 64);
    t5  += __shfl_xor(t5, o, 64);
    mr  += __shfl_xor(mr, o, 64);
  }
  __shared__ float red[4][4];
  const int wv = tid >> 6, lane = tid & 63;
  if (lane == 0) { red[wv][0] = nll; red[wv][1] = t1; red[wv][2] = t5; red[wv][3] = mr; }
  __syncthreads();
  if (tid == 0) {
    float a = 0.f, b = 0.f, cc = 0.f, d = 0.f;
    #pragma unroll
    for (int k = 0; k < 4; ++k) { a += red[k][0]; b += red[k][1]; cc += red[k][2]; d += red[k][3]; }
    g_part4[blockIdx.x * 4 + 0] = a;
    g_part4[blockIdx.x * 4 + 1] = b;
    g_part4[blockIdx.x * 4 + 2] = cc;
    g_part4[blockIdx.x * 4 + 3] = d;
    __builtin_amdgcn_fence(__ATOMIC_RELEASE, "agent");
    const int old = __hip_atomic_fetch_add(&g_tick2, 1,
                        __ATOMIC_RELAXED, __HIP_MEMORY_SCOPE_AGENT);
    if (old == 31) {                   // last block finalizes, fixed order
      __builtin_amdgcn_fence(__ATOMIC_ACQUIRE, "agent");
      float A = 0.f, B = 0.f, C = 0.f, D = 0.f;
      for (int k = 0; k < 32; ++k) {
        A += g_part4[k * 4 + 0];
        B += g_part4[k * 4 + 1];
        C += g_part4[k * 4 + 2];
        D += g_part4[k * 4 + 3];
      }
      out[0] = A / (float)NTOT;
      out[1] = B / (float)NTOT;
      out[2] = C / (float)NTOT;
      out[3] = 1.f + D / (float)NTOT;
    }
  }
}

extern "C" void kernel_launch(void* const* d_in, const int* in_sizes, int n_in,
                              void* d_out, int out_size, void* d_ws, size_t ws_size,
                              hipStream_t stream) {
  const float* f1 = (const float*)d_in[0];
  const float* f2 = (const float*)d_in[1];
  float* out = (float*)d_out;

  knorm  <<<dim3(2048), dim3(256), 0, stream>>>(f1, f2);
  kmain  <<<dim3(NBLK), dim3(256), 0, stream>>>();
  kredfin<<<dim3(32),   dim3(256), 0, stream>>>(out);
}

// Round 6
// 147.282 us; speedup vs baseline: 2.2237x; 2.2237x over previous
//
#include <hip/hip_runtime.h>
#include <math.h>
#include <stdint.h>

#define NTOT   8192
#define HALF_N 4096
#define DIM    512
#define INV_T  14.2857142857142857f   // 1/0.07
#define NTILE  64                     // 8192 / 128
#define NBLK   2080                   // 64*65/2 triangular; 2080 % 8 == 0

using s16x8 = __attribute__((ext_vector_type(8))) short;
using f32x4 = __attribute__((ext_vector_type(4))) float;

// Scratch in static device globals (fully rewritten every call; no d_ws use).
__device__ unsigned short g_fnb[NTOT * DIM];   // normalized bf16 matrix, 8 MB
__device__ float g_pos[NTOT];
__device__ float g_ps[(size_t)NTILE * NTOT];   // per-slot sumexp partials, 2 MB
__device__ int   g_pc[(size_t)NTILE * NTOT];   // per-slot count partials, 2 MB
__device__ float g_part4[32 * 4];              // per-block scalar partials (kredfin)
__device__ int   g_tick2;                      // kredfin last-block ticket

// super-tile decode tables: 4x4 upper-triangle of 16x16 slab groups.
// sizes: diag super = 136 (16*17/2), full super = 256. (R4-verified decode;
// proven FETCH 112->48 MB. Innocent in both R4/R5 regressions.)
__constant__ int c_pre[11] = {0,136,392,648,904,1040,1296,1552,1688,1944,2080};
__constant__ int c_gi[10]  = {0,0,0,0,1,1,1,2,2,3};
__constant__ int c_gj[10]  = {0,1,2,3,1,2,3,2,3,3};

__device__ __forceinline__ float bf2f(unsigned short u) {
  union { unsigned int i; float f; } v; v.i = ((unsigned int)u) << 16; return v.f;
}
__device__ __forceinline__ unsigned short f2bf(float x) {
  union { float f; unsigned int i; } v; v.f = x;
  unsigned int u = v.i;
  return (unsigned short)((u + 0x7FFFu + ((u >> 16) & 1u)) >> 16);
}

// async global->LDS, 16 B per lane. LDS dest is wave-uniform base + lane*16.
__device__ __forceinline__ void gload16(const unsigned short* g, unsigned short* l) {
  __builtin_amdgcn_global_load_lds(
      (const __attribute__((address_space(1))) unsigned int*)g,
      (__attribute__((address_space(3))) unsigned int*)l, 16, 0, 0);
}

// ---------------- kernel 1: normalize pairs -> bf16, pos, reset ticket ----------------
__global__ __launch_bounds__(256) void knorm(const float* __restrict__ f1,
                                             const float* __restrict__ f2) {
  const int tid  = threadIdx.x;
  const int wv   = tid >> 6;
  const int pi   = wv >> 1;            // pair within block
  const int half = wv & 1;             // 0: f1 row, 1: f2 row
  const int lane = tid & 63;
  const int b    = blockIdx.x * 2 + pi;
  const int row  = b + half * HALF_N;

  if (blockIdx.x == 0 && tid == 0)
    __hip_atomic_store(&g_tick2, 0, __ATOMIC_RELAXED, __HIP_MEMORY_SCOPE_AGENT);

  const float* src = (half == 0) ? (f1 + (size_t)b * DIM) : (f2 + (size_t)b * DIM);
  float4 v0 = ((const float4*)src)[lane];
  float4 v1 = ((const float4*)src)[lane + 64];
  float ss = v0.x*v0.x + v0.y*v0.y + v0.z*v0.z + v0.w*v0.w
           + v1.x*v1.x + v1.y*v1.y + v1.z*v1.z + v1.w*v1.w;
  #pragma unroll
  for (int o = 32; o >= 1; o >>= 1) ss += __shfl_xor(ss, o, 64);
  const float sc = 1.0f / fmaxf(sqrtf(ss), 1e-8f);
  ushort4 h0, h1;
  h0.x = f2bf(v0.x * sc); h0.y = f2bf(v0.y * sc);
  h0.z = f2bf(v0.z * sc); h0.w = f2bf(v0.w * sc);
  h1.x = f2bf(v1.x * sc); h1.y = f2bf(v1.y * sc);
  h1.z = f2bf(v1.z * sc); h1.w = f2bf(v1.w * sc);
  ushort4* dst = (ushort4*)(g_fnb + (size_t)row * DIM);
  dst[lane]      = h0;
  dst[lane + 64] = h1;

  // pos[b] = <fn_b, fn_{b+4096}> on the same bf16 values the GEMM uses
  __shared__ ushort4 sh[2][64][2];
  if (half == 1) { sh[pi][lane][0] = h0; sh[pi][lane][1] = h1; }
  __syncthreads();
  if (half == 0) {
    const ushort4 p0 = sh[pi][lane][0], p1 = sh[pi][lane][1];
    float s = bf2f(h0.x)*bf2f(p0.x) + bf2f(h0.y)*bf2f(p0.y)
            + bf2f(h0.z)*bf2f(p0.z) + bf2f(h0.w)*bf2f(p0.w)
            + bf2f(h1.x)*bf2f(p1.x) + bf2f(h1.y)*bf2f(p1.y)
            + bf2f(h1.z)*bf2f(p1.z) + bf2f(h1.w)*bf2f(p1.w);
    #pragma unroll
    for (int o = 32; o >= 1; o >>= 1) s += __shfl_xor(s, o, 64);
    if (lane == 0) { g_pos[b] = s; g_pos[b + HALF_N] = s; }
  }
}

// ---------------- kernel 2: symmetric fused GEMM, atomic-free epilogue ----------------
// R6: proven pieces only.
//  - R3 structure: plain slot stores, no fences/tickets in the hot kernel
//    (R4 lesson: agent-scope acq_rel RMWs force per-XCD L2 writebacks).
//  - R4 super-tile schedule: 16x16-slab supers keep each XCD's working set
//    ~4 MB = one L2 (proven FETCH 112->48 MB).
//  - LDS scratch aliased onto As -> LDS exactly 32 KB -> HW fits 5 blocks/CU
//    by LDS math alone. __launch_bounds__ stays (256,4): R5 lesson -- the
//    2nd arg is a VGPR-allocation floor; (256,5) capped VGPR at ~96 and
//    spilled the 64-reg accumulator (WRITE_SIZE 52->654 MB, 3x slower).
__global__ __launch_bounds__(256, 4) void kmain() {
  __shared__ __align__(16) unsigned short As[128 * 64];   // 16 KB
  __shared__ __align__(16) unsigned short Bs[128 * 64];   // 16 KB
  // epilogue scratch aliased onto As (guarded by a barrier after the K-loop)
  float* sRowS = reinterpret_cast<float*>(As);            // 128 f
  int*   sRowC = reinterpret_cast<int*>(sRowS + 128);     // 128 i
  float* sColS = reinterpret_cast<float*>(sRowC + 128);   // 128 f
  int*   sColC = reinterpret_cast<int*>(sColS + 128);     // 128 i

  // XCD swizzle: contiguous t-range of 260 per XCD, then super-tile decode
  const int t_sw = (blockIdx.x & 7) * (NBLK / 8) + (blockIdx.x >> 3);
  int sp = 0;
  while (t_sw >= c_pre[sp + 1]) ++sp;
  int l = t_sw - c_pre[sp];
  int lbi, lbj;
  if (c_gi[sp] == c_gj[sp]) {          // diagonal super: triangular 16
    int r16 = 16; lbi = 0;
    while (l >= r16) { l -= r16; --r16; ++lbi; }
    lbj = lbi + l;
  } else {                             // full super: row-major (A-slab runs)
    lbi = l >> 4; lbj = l & 15;
  }
  const int bi = c_gi[sp] * 16 + lbi;
  const int bj = c_gj[sp] * 16 + lbj;
  const bool offdiag = (bi != bj);
  const int i0 = bi * 128, j0 = bj * 128;

  const int tid  = threadIdx.x;
  const int lane = tid & 63;
  const int w    = tid >> 6;
  const int wr   = (w >> 1) * 64;   // wave row base
  const int wc   = (w & 1) * 64;    // wave col base
  const int lrow = lane & 15;
  const int lq   = lane >> 4;

  // staging: wave w covers tile rows [w*32, w*32+32) in 4 chunks of 8 rows.
  // Linear LDS dest; inverse-XOR-swizzled global source (rule #21).
  const int rsub = lane >> 3;
  const int lcb  = (lane & 7) ^ rsub;
  const unsigned short* Ag = g_fnb + (size_t)(i0 + w * 32 + rsub) * DIM + lcb * 8;
  const unsigned short* Bg = g_fnb + (size_t)(j0 + w * 32 + rsub) * DIM + lcb * 8;
  unsigned short* Al = &As[w * 32 * 64];
  unsigned short* Bl = &Bs[w * 32 * 64];

  f32x4 acc[4][4];
  #pragma unroll
  for (int a = 0; a < 4; ++a)
    #pragma unroll
    for (int bb = 0; bb < 4; ++bb) { acc[a][bb][0]=0.f; acc[a][bb][1]=0.f; acc[a][bb][2]=0.f; acc[a][bb][3]=0.f; }

  const unsigned short* Bls = offdiag ? (const unsigned short*)Bs
                                      : (const unsigned short*)As;

  for (int kt = 0; kt < 8; ++kt) {
    __syncthreads();                       // prev compute done, LDS reusable
    const int kb = kt * 64;
    #pragma unroll
    for (int q = 0; q < 4; ++q) {
      gload16(Ag + (size_t)(q * 8) * DIM + kb, Al + q * 512);
      if (offdiag) gload16(Bg + (size_t)(q * 8) * DIM + kb, Bl + q * 512);
    }
    __syncthreads();                       // vmcnt(0) drains here -> tile kt visible

    #pragma unroll
    for (int kk = 0; kk < 2; ++kk) {
      s16x8 af[4], bf[4];
      #pragma unroll
      for (int mi = 0; mi < 4; ++mi) {
        const int r = wr + mi * 16 + lrow;
        af[mi] = *(const s16x8*)(&As[r * 64 + (((kk * 4 + lq) ^ (lrow & 7)) * 8)]);
      }
      #pragma unroll
      for (int ni = 0; ni < 4; ++ni) {
        const int r = wc + ni * 16 + lrow;
        bf[ni] = *(const s16x8*)(&Bls[r * 64 + (((kk * 4 + lq) ^ (lrow & 7)) * 8)]);
      }
      #pragma unroll
      for (int mi = 0; mi < 4; ++mi)
        #pragma unroll
        for (int ni = 0; ni < 4; ++ni)
          acc[mi][ni] = __builtin_amdgcn_mfma_f32_16x16x32_bf16(af[mi], bf[ni], acc[mi][ni], 0, 0, 0);
    }
  }

  // ---- epilogue: LDS-combine partials, plain slot stores (no global atomics) ----
  __syncthreads();   // all waves' LDS reads done -> safe to reuse As as scratch
  if (tid < 128) { sRowS[tid] = 0.f; sRowC[tid] = 0; sColS[tid] = 0.f; sColC[tid] = 0; }
  __syncthreads();

  // row side (always): 2 waves contribute per row (wc=0 / wc=64)
  #pragma unroll
  for (int mi = 0; mi < 4; ++mi) {
    #pragma unroll
    for (int r = 0; r < 4; ++r) {
      const int ridx = wr + mi * 16 + lq * 4 + r;     // 0..127
      const int i  = i0 + ridx;
      const float pv = g_pos[i];
      float s = 0.f; int c = 0;
      #pragma unroll
      for (int ni = 0; ni < 4; ++ni) {
        const int j = j0 + wc + ni * 16 + lrow;
        const float v = acc[mi][ni][r];
        const float e = __expf(v * INV_T);
        const bool diag = (j == i);
        s += diag ? 0.f : e;
        c += (!diag && (j != (i ^ HALF_N)) && (v > pv)) ? 1 : 0;
      }
      #pragma unroll
      for (int o = 1; o < 16; o <<= 1) {
        s += __shfl_xor(s, o, 64);
        c += __shfl_xor(c, o, 64);
      }
      if (lrow == 0) {
        atomicAdd(&sRowS[ridx], s);
        atomicAdd(&sRowC[ridx], c);
      }
    }
  }

  // col side (off-diagonal only): 2 waves contribute per col (wr=0 / wr=64)
  if (offdiag) {
    #pragma unroll
    for (int ni = 0; ni < 4; ++ni) {
      const int cidx = wc + ni * 16 + lrow;           // 0..127
      const int j  = j0 + cidx;
      const float pj = g_pos[j];
      float s = 0.f; int c = 0;
      #pragma unroll
      for (int mi = 0; mi < 4; ++mi) {
        #pragma unroll
        for (int r = 0; r < 4; ++r) {
          const int i = i0 + wr + mi * 16 + lq * 4 + r;
          const float v = acc[mi][ni][r];
          s += __expf(v * INV_T);
          c += ((i != (j ^ HALF_N)) && (v > pj)) ? 1 : 0;
        }
      }
      s += __shfl_xor(s, 16, 64); s += __shfl_xor(s, 32, 64);
      c += __shfl_xor(c, 16, 64); c += __shfl_xor(c, 32, 64);
      if (lq == 0) {
        atomicAdd(&sColS[cidx], s);
        atomicAdd(&sColC[cidx], c);
      }
    }
  }
  __syncthreads();

  // slot stores: row side -> slab bi slot bj; col side -> slab bj slot bi
  if (tid < 128) {
    g_ps[(size_t)bj * NTOT + i0 + tid] = sRowS[tid];
    g_pc[(size_t)bj * NTOT + i0 + tid] = sRowC[tid];
  } else if (offdiag && tid < 256) {
    const int r2 = tid - 128;
    g_ps[(size_t)bi * NTOT + j0 + r2] = sColS[r2];
    g_pc[(size_t)bi * NTOT + j0 + r2] = sColC[r2];
  }
}

// ---------------- kernel 3: fold slots + finalize (last-block ticket) ----------------
__global__ __launch_bounds__(256) void kredfin(float* __restrict__ out) {
  const int tid = threadIdx.x;
  const int i = blockIdx.x * 256 + tid;            // 32 blocks x 256 = 8192 rows
  float s = 0.f; int c = 0;
  #pragma unroll 8
  for (int sl = 0; sl < NTILE; ++sl) {
    s += g_ps[(size_t)sl * NTOT + i];
    c += g_pc[(size_t)sl * NTOT + i];
  }
  float nll = -g_pos[i] * INV_T + logf(s);
  float t1 = (c == 0) ? 1.f : 0.f;
  float t5 = (c < 5) ? 1.f : 0.f;
  float mr = (float)c;
  #pragma unroll
  for (int o = 32; o >= 1; o >>= 1) {
    nll += __shfl_xor(nll, o, 64);
    t1  += __shfl_xor(t1, o, 64);
    t5  += __shfl_xor(t5, o, 64);
    mr  += __shfl_xor(mr, o, 64);
  }
  __shared__ float red[4][4];
  const int wv = tid >> 6, lane = tid & 63;
  if (lane == 0) { red[wv][0] = nll; red[wv][1] = t1; red[wv][2] = t5; red[wv][3] = mr; }
  __syncthreads();
  if (tid == 0) {
    float a = 0.f, b = 0.f, cc = 0.f, d = 0.f;
    #pragma unroll
    for (int k = 0; k < 4; ++k) { a += red[k][0]; b += red[k][1]; cc += red[k][2]; d += red[k][3]; }
    g_part4[blockIdx.x * 4 + 0] = a;
    g_part4[blockIdx.x * 4 + 1] = b;
    g_part4[blockIdx.x * 4 + 2] = cc;
    g_part4[blockIdx.x * 4 + 3] = d;
    __builtin_amdgcn_fence(__ATOMIC_RELEASE, "agent");
    const int old = __hip_atomic_fetch_add(&g_tick2, 1,
                        __ATOMIC_RELAXED, __HIP_MEMORY_SCOPE_AGENT);
    if (old == 31) {                   // last block finalizes, fixed order
      __builtin_amdgcn_fence(__ATOMIC_ACQUIRE, "agent");
      float A = 0.f, B = 0.f, C = 0.f, D = 0.f;
      for (int k = 0; k < 32; ++k) {
        A += g_part4[k * 4 + 0];
        B += g_part4[k * 4 + 1];
        C += g_part4[k * 4 + 2];
        D += g_part4[k * 4 + 3];
      }
      out[0] = A / (float)NTOT;
      out[1] = B / (float)NTOT;
      out[2] = C / (float)NTOT;
      out[3] = 1.f + D / (float)NTOT;
    }
  }
}

extern "C" void kernel_launch(void* const* d_in, const int* in_sizes, int n_in,
                              void* d_out, int out_size, void* d_ws, size_t ws_size,
                              hipStream_t stream) {
  const float* f1 = (const float*)d_in[0];
  const float* f2 = (const float*)d_in[1];
  float* out = (float*)d_out;

  knorm  <<<dim3(2048), dim3(256), 0, stream>>>(f1, f2);
  kmain  <<<dim3(NBLK), dim3(256), 0, stream>>>();
  kredfin<<<dim3(32),   dim3(256), 0, stream>>>(out);
}